// Round 12
// baseline (3452.049 us; speedup 1.0000x reference)
//
#include <hip/hip_runtime.h>
#include <hip/hip_bf16.h>
#include <cstdint>
#include <cstddef>

#define T_STEPS 1024
#define BATCH   128
#define INF     128   // used input features (130 minus last 2)
#define HID     512
#define NBLK    256   // 32 ug (16 units) x 8 bg (16 batch), 1 block/CU
#define NTHR    256   // 4 waves; wave w = u-tile (4 units x 4 gates), full k=640
#define PK      648   // padded k stride (fp16 units) in LDS Z plane

typedef _Float16 f16x8 __attribute__((ext_vector_type(8)));
typedef float    f32x4 __attribute__((ext_vector_type(4)));

static __device__ __forceinline__ unsigned short f16b(float v) {
  _Float16 h = (_Float16)v;
  unsigned short u;
  __builtin_memcpy(&u, &h, 2);
  return u;
}
static __device__ __forceinline__ float fsigmoid(float x) {
  return 1.f / (1.f + __expf(-x));
}
static __device__ __forceinline__ float ftanh(float x) {
  return 1.f - 2.f / (__expf(2.f * x) + 1.f);
}

// ---------------- pre-pass kernels ----------------

// xp[t*8+bg][c 16][k 128] fp16
__global__ __launch_bounds__(256) void k_prep_x(const float* __restrict__ in,
                                                unsigned short* __restrict__ xp)
{
  int t = blockIdx.x >> 3, bg = blockIdx.x & 7;
  int tid = threadIdx.x;
  size_t base = (size_t)blockIdx.x * 2048;
  #pragma unroll
  for (int rep = 0; rep < 8; ++rep) {
    int idx = rep * 256 + tid;           // 0..2047
    int c = idx >> 7, k = idx & 127;
    float v = in[((size_t)(bg * 16 + c) * T_STEPS + t) * 130 + k];
    xp[base + c * 128 + k] = f16b(v);
  }
}

// W A-fragments fp16, per-lane MFMA layout.
// blk = (ug*4+u4)*20 + s   (2560 blocks x 64 threads)
// tile rows m = u_loc*4 + gate -> Grow = gate*HID + ug*16 + u4*4 + u_loc
// A lane map (16x16x32): row = l&15, k = (l>>4)*8 + j
__global__ __launch_bounds__(64) void k_prep_w(const float* __restrict__ Wih,
                                               const float* __restrict__ Whh,
                                               unsigned short* __restrict__ wf)
{
  int blk = blockIdx.x;
  int s = blk % 20; int r = blk / 20;
  int u4 = r & 3; int ug = r >> 2;
  int l = threadIdx.x;
  int m = l & 15;
  int Grow = (m & 3) * HID + ug * 16 + u4 * 4 + (m >> 2);
  int kb = s * 32 + (l >> 4) * 8;
  unsigned short o[8];
  #pragma unroll
  for (int j = 0; j < 8; ++j) {
    float v = (kb + j < INF) ? Wih[(size_t)Grow * INF + kb + j]
                             : Whh[(size_t)Grow * HID + (kb + j - INF)];
    o[j] = f16b(v);
  }
  unsigned short* d = wf + ((size_t)blk * 64 + l) * 8;
  #pragma unroll
  for (int j = 0; j < 8; ++j) d[j] = o[j];
}

// hp0[bg][c 16][u2 256] u64 = tag0<<32 | (f16(h0[b][2u]) | f16(h0[b][2u+1])<<16)
// hp1 zeroed (tag 0 never matches an odd expected step).  32768 words total.
__global__ __launch_bounds__(256) void k_prep_h(const float* __restrict__ h0,
                                                unsigned long long* __restrict__ hp0,
                                                unsigned long long* __restrict__ hp1)
{
  int idx = blockIdx.x * 256 + threadIdx.x;   // 0..32767
  int bg = idx >> 12;
  int r = idx & 4095;
  int c = r >> 8, u2 = r & 255;
  float v0 = h0[(size_t)(bg * 16 + c) * HID + 2 * u2];
  float v1 = h0[(size_t)(bg * 16 + c) * HID + 2 * u2 + 1];
  hp0[idx] = (unsigned long long)((unsigned)f16b(v0) | ((unsigned)f16b(v1) << 16));
  hp1[idx] = 0ull;
}

// ---------------- persistent MFMA LSTM (tagged u64 h, 1-RT sync) ----------------
// 256 blocks = 32 ug (16 units) x 8 bg (16 b). 256 thr = 4 waves.
// Wave w owns u-tile (units ug*16+w*4..+3, rows = u_loc*4+gate), full k=640.
// Sync: h words carry their own step tag; consumers validate per-word and
// selectively reload. No flags, no producer drain. One barrier per step.
__global__ __launch_bounds__(NTHR, 1) void k_persist(
    const unsigned short* __restrict__ xp,   // [t*8+bg][16][128] fp16
    const unsigned short* __restrict__ wf,   // A-fragments fp16
    const float* __restrict__ bih, const float* __restrict__ bhh,
    unsigned long long* __restrict__ hp0,    // [8][16][256] tagged u64, parity 0
    unsigned long long* __restrict__ hp1,    // parity 1
    const float* __restrict__ c0,            // [128][512]
    const int* __restrict__ len,
    float* __restrict__ out)                 // [128][512]
{
  __shared__ short zpl[2][16][PK];           // double-buffered Z plane

  const int blk = blockIdx.x;
  const int ug = blk & 31, bg = blk >> 5;
  const int tid = threadIdx.x;
  const int w = tid >> 6, l = tid & 63;
  const int cB = l & 15, gch = l >> 4;

  // ---- load 20 W A-fragments into NAMED registers (once; AGPR-resident)
  const uint4* wfq = (const uint4*)wf;
  const int fb = (ug * 4 + w) * 20;
#define LDW(s_) (*reinterpret_cast<const f16x8*>(&wfq[(size_t)(fb + (s_)) * 64 + l]))
  f16x8 A0 = LDW(0),  A1 = LDW(1),  A2 = LDW(2),  A3 = LDW(3),  A4 = LDW(4);
  f16x8 A5 = LDW(5),  A6 = LDW(6),  A7 = LDW(7),  A8 = LDW(8),  A9 = LDW(9);
  f16x8 A10 = LDW(10), A11 = LDW(11), A12 = LDW(12), A13 = LDW(13), A14 = LDW(14);
  f16x8 A15 = LDW(15), A16 = LDW(16), A17 = LDW(17), A18 = LDW(18), A19 = LDW(19);
#undef LDW
  asm volatile("" : "+v"(A0), "+v"(A1), "+v"(A2), "+v"(A3), "+v"(A4),
                    "+v"(A5), "+v"(A6), "+v"(A7), "+v"(A8), "+v"(A9),
                    "+v"(A10), "+v"(A11), "+v"(A12), "+v"(A13), "+v"(A14),
                    "+v"(A15), "+v"(A16), "+v"(A17), "+v"(A18), "+v"(A19));

  // ---- per-cell state: every lane owns cell (unit hu, batch cb)
  const int cb = l & 15;
  const int uloc = l >> 4;
  const int hu = ug * 16 + w * 4 + uloc;
  const int gb = bg * 16 + cb;
  float c_reg = c0[(size_t)gb * HID + hu];
  const int mylen = len[gb];
  float bsq[4];
  #pragma unroll
  for (int g = 0; g < 4; ++g) bsq[g] = bih[g * HID + hu] + bhh[g * HID + hu];

  // h slab assignment: thread validates/stages 16 u64 words
  const int hc = tid >> 4, hs = tid & 15;    // c row, sub-index

  for (int t = 0; t < T_STEPS; ++t) {
    const unsigned long long* hq = ((t & 1) ? hp1 : hp0) + (size_t)bg * 4096;
    unsigned long long*       hd = ((t & 1) ? hp0 : hp1) + (size_t)bg * 4096;
    short (*zb)[PK] = zpl[t & 1];

    // ---- x load (independent of h)
    uint4 xv = ((const uint4*)(xp + (size_t)(t * 8 + bg) * 2048))[tid];

    // ---- issue tagged h bulk load (16 u64, coalesced per 16-lane group)
    unsigned long long hch[16];
    #pragma unroll
    for (int j = 0; j < 16; ++j)
      hch[j] = __hip_atomic_load(hq + hc * 256 + j * 16 + hs,
                                 __ATOMIC_RELAXED, __HIP_MEMORY_SCOPE_AGENT);

    // ---- stage x while h is in flight
    *(uint4*)((char*)&zb[tid >> 4][0] + (tid & 15) * 16) = xv;

    // ---- validate tags; selectively reload stale words
    for (;;) {
      int bad = 0;
      #pragma unroll
      for (int j = 0; j < 16; ++j)
        if ((unsigned)(hch[j] >> 32) != (unsigned)t) bad = 1;
      if (!__any(bad)) break;
      __builtin_amdgcn_s_sleep(1);
      #pragma unroll
      for (int j = 0; j < 16; ++j)
        if ((unsigned)(hch[j] >> 32) != (unsigned)t)
          hch[j] = __hip_atomic_load(hq + hc * 256 + j * 16 + hs,
                                     __ATOMIC_RELAXED, __HIP_MEMORY_SCOPE_AGENT);
    }

    // ---- stage h payloads: word (hc, j*16+hs) -> units [2*(j*16+hs), +1]
    {
      unsigned* zr = (unsigned*)&zb[hc][128];
      #pragma unroll
      for (int j = 0; j < 16; ++j)
        zr[j * 16 + hs] = (unsigned)hch[j];
    }
    __syncthreads();   // staging complete -> MFMA may read

    // ---- MFMA: 20 k-steps x 1 fp16 MFMA, full k=640
    f32x4 aE = {0, 0, 0, 0}, aO = {0, 0, 0, 0};
    const short* zr = &zb[cB][0];
#define KS(s_, AF, ACC) \
  { f16x8 B = *(const f16x8*)(zr + (s_) * 32 + gch * 8); \
    ACC = __builtin_amdgcn_mfma_f32_16x16x32_f16(AF, B, ACC, 0, 0, 0); }
    KS(0, A0, aE)  KS(1, A1, aO)  KS(2, A2, aE)  KS(3, A3, aO)
    KS(4, A4, aE)  KS(5, A5, aO)  KS(6, A6, aE)  KS(7, A7, aO)
    KS(8, A8, aE)  KS(9, A9, aO)  KS(10, A10, aE) KS(11, A11, aO)
    KS(12, A12, aE) KS(13, A13, aO) KS(14, A14, aE) KS(15, A15, aO)
    KS(16, A16, aE) KS(17, A17, aO) KS(18, A18, aE) KS(19, A19, aO)
#undef KS

    // ---- in-lane cell update: acc[r] = gate r of (hu, cb)
    float s0 = aE[0] + aO[0] + bsq[0];
    float s1 = aE[1] + aO[1] + bsq[1];
    float s2 = aE[2] + aO[2] + bsq[2];
    float s3 = aE[3] + aO[3] + bsq[3];
    float iv = fsigmoid(s0);
    float fv = fsigmoid(s1);
    float gv = ftanh(s2);
    float ov = fsigmoid(s3);
    c_reg = fv * c_reg + iv * gv;
    float h2 = ov * ftanh(c_reg);

    // ---- pack unit-pair + tag (t+1), one u64 agent store per even u_loc lane
    unsigned hb = f16b(h2);
    unsigned other = __shfl_xor(hb, 16);
    if ((uloc & 1) == 0) {
      unsigned long long word = ((unsigned long long)(unsigned)(t + 1) << 32)
                              | (unsigned long long)(hb | (other << 16));
      __hip_atomic_store(hd + cb * 256 + (ug * 8 + w * 2 + (uloc >> 1)), word,
                         __ATOMIC_RELAXED, __HIP_MEMORY_SCOPE_AGENT);
    }
    if (t == mylen - 1) out[(size_t)gb * HID + hu] = h2;
    // no trailing barrier: tags gate peers; zpl double-buffered.
  }
}

// ---------------- launch ----------------
extern "C" void kernel_launch(void* const* d_in, const int* in_sizes, int n_in,
                              void* d_out, int out_size, void* d_ws, size_t ws_size,
                              hipStream_t stream)
{
  const float* inputs = (const float*)d_in[0];
  const int*   len    = (const int*)  d_in[1];
  const float* h0     = (const float*)d_in[2];
  const float* c0     = (const float*)d_in[3];
  const float* Wih    = (const float*)d_in[4];
  const float* Whh    = (const float*)d_in[5];
  const float* bih    = (const float*)d_in[6];
  const float* bhh    = (const float*)d_in[7];
  float* out = (float*)d_out;

  char* p = (char*)d_ws;
  unsigned short* xp = (unsigned short*)p; p += (size_t)T_STEPS * 8 * 2048 * 2;      // 32 MB
  unsigned short* wf = (unsigned short*)p; p += (size_t)2560 * 64 * 8 * 2;           // 2.6 MB
  unsigned long long* hp0 = (unsigned long long*)p; p += (size_t)8 * 4096 * 8;       // 256 KB
  unsigned long long* hp1 = (unsigned long long*)p; p += (size_t)8 * 4096 * 8;       // 256 KB

  k_prep_x<<<T_STEPS * 8, 256, 0, stream>>>(inputs, xp);
  k_prep_w<<<2560, 64, 0, stream>>>(Wih, Whh, wf);
  k_prep_h<<<128, 256, 0, stream>>>(h0, hp0, hp1);

  void* args[] = {(void*)&xp, (void*)&wf, (void*)&bih, (void*)&bhh,
                  (void*)&hp0, (void*)&hp1, (void*)&c0, (void*)&len,
                  (void*)&out};
  (void)hipLaunchCooperativeKernel((void*)k_persist, dim3(NBLK), dim3(NTHR),
                                   args, 0, stream);
}